// Round 3
// baseline (970.389 us; speedup 1.0000x reference)
//
#include <hip/hip_runtime.h>

// DeepTreeLSTM on MI355X (gfx950). Inputs fp32 (verified R3); dtype probe kept.
// Tree: 511 nodes, level d has 2^d nodes. h level-major: base_d = 256*(2^d-1)*256.
//
// R10 (resubmit; R2 bench was an infra failure, no counters): R9's weight hoist
// spilled (VGPR=64 cap at 1024 thr -> 403MB scratch FETCH).
// -> weights back to in-loop L2 loads (16 waves hide), launch_bounds(1024,4).
// leaf/level7 were write-amplified (scalar 2B stores, partial-line evictions,
// 313MB moved vs 134 ideal) -> LDS bounce buffer + full-cache-line short8 stores.
//
// Workspace:
//   h_all  bf16 [0,           66,977,792)    (only levels 7,8 written now)
//   cbufA  bf16 [66,977,792, 100,532,224)   c8 (leaf out)
//   cbufB  bf16 [100,532,224,117,309,440)   c7 (level7 out)
//   arena  bf16 [117,309,440,118,401,928)   converted weights/biases/emo
//   flag   int  [118,401,928,118,401,932)

typedef __attribute__((ext_vector_type(8))) short short8;
typedef __attribute__((ext_vector_type(4))) float f32x4;

#define HB 256
#define BASE8 16711680   // 256*255*256
#define BASE7 8323072    // 256*127*256

#define A_WIOU 0
#define A_UIOU 196608
#define A_BIOU 393216
#define A_UFW  393984
#define A_UFB  459520
#define A_WIN  459776
#define A_BIN  529408
#define A_WMID 529536
#define A_BMID 537728
#define A_WOUT 537792
#define A_BOUT 538048
#define A_EMO  538052
#define A_TOT  546244

__device__ __forceinline__ float b2f(short s){
  union { unsigned u; float f; } v; v.u = ((unsigned)(unsigned short)s) << 16; return v.f;
}
__device__ __forceinline__ short f2b(float f){
  union { float f; unsigned u; } v; v.f = f;
  unsigned r = v.u + 0x7fffu + ((v.u >> 16) & 1u);   // RNE
  return (short)(unsigned short)(r >> 16);
}
__device__ __forceinline__ float fsig(float x){ return 1.f / (1.f + __expf(-x)); }
__device__ __forceinline__ float ftanh(float x){
  x = fminf(fmaxf(x, -10.f), 10.f);
  float e = __expf(2.f * x);
  return (e - 1.f) / (e + 1.f);
}

// LDS A-tile (leaf/level7): 128 rows x 256 k, XOR-swizzled 8-short groups (64 KB).
__device__ __forceinline__ int swz(int row, int g){   // g = k>>3
  return row * 256 + (((g ^ (row & 31)) & 31) << 3);
}

// ---------------- dtype probe ------------------------------------------------------------
__global__ __launch_bounds__(256)
void probe_kernel(const void* __restrict__ X, int* __restrict__ flag)
{
  __shared__ int sh[256];
  const int t = threadIdx.x;
  const unsigned short* p = (const unsigned short*)X;
  int cnt = 0;
  #pragma unroll
  for (int k = 0; k < 16; ++k){
    unsigned e = (p[t * 16 + k] >> 7) & 0xFFu;
    cnt += (e >= 0xC0u);
  }
  sh[t] = cnt; __syncthreads();
  for (int s = 128; s > 0; s >>= 1){ if (t < s) sh[t] += sh[t + s]; __syncthreads(); }
  if (t == 0) *flag = (sh[0] >= 16) ? 1 : 0;
}

// ---------------- convert params into bf16 arena -----------------------------------------
__global__ __launch_bounds__(256)
void conv_kernel(const void* s0, const void* s1, const void* s2, const void* s3,
                 const void* s4, const void* s5, const void* s6, const void* s7,
                 const void* s8, const void* s9, const void* s10, const void* s11,
                 short* __restrict__ arena, const int* __restrict__ flag)
{
  const int i = blockIdx.x * 256 + threadIdx.x;
  if (i >= A_TOT) return;
  const int bounds[13] = {A_WIOU, A_UIOU, A_BIOU, A_UFW, A_UFB, A_WIN, A_BIN,
                          A_WMID, A_BMID, A_WOUT, A_BOUT, A_EMO, A_TOT};
  const void* sp[12] = {s0,s1,s2,s3,s4,s5,s6,s7,s8,s9,s10,s11};
  int seg = 0;
  #pragma unroll
  for (int k = 1; k < 12; ++k) if (i >= bounds[k]) seg = k;
  const int j = i - bounds[seg];
  const float v = (*flag) ? ((const float*)sp[seg])[j] : b2f(((const short*)sp[seg])[j]);
  arena[i] = f2b(v);
}

// ---------------- leaf: 128-row tile, wave = 64 rows x 16 cols x 3 gates -----------------
// grid (512), block 256. R10: outputs bounce through LDS, stored as full 64B lines.
__global__ __launch_bounds__(256, 2)
void leaf_kernel(const void* __restrict__ X, const short* __restrict__ arena,
                 const int* __restrict__ flag,
                 short* __restrict__ hall, short* __restrict__ cout)
{
  __shared__ short At[32768];
  __shared__ short Oh[4096];     // 128 rows x 32 cols (current s-slice)
  __shared__ short Oc[4096];
  const int t = threadIdx.x, lane = t & 63, w = t >> 6;
  const int l15 = lane & 15, quad = lane >> 4;
  const int rh = w >> 1, cl = w & 1;
  const int rowbase = 128 * blockIdx.x;
  const size_t grow0 = ((size_t)(rowbase >> 8) * 511 + 255 + (rowbase & 255)) * HB;
  const bool isf = (*flag) != 0;

  #pragma unroll
  for (int i = 0; i < 16; ++i){
    const int gi = i * 256 + t;
    const int row = gi >> 5, g = gi & 31;
    short8 v;
    if (isf){
      const float* p = (const float*)X + grow0 + (size_t)row * HB + g * 8;
      const float4 u = *(const float4*)p;
      const float4 q = *(const float4*)(p + 4);
      v[0]=f2b(u.x); v[1]=f2b(u.y); v[2]=f2b(u.z); v[3]=f2b(u.w);
      v[4]=f2b(q.x); v[5]=f2b(q.y); v[6]=f2b(q.z); v[7]=f2b(q.w);
    } else {
      v = *(const short8*)((const short*)X + grow0 + (size_t)row * HB + g * 8);
    }
    *(short8*)&At[swz(row, g)] = v;
  }
  __syncthreads();

  #pragma unroll
  for (int s = 0; s < 8; ++s){
    const int colh = s * 32 + cl * 16 + l15;
    const short* pI = arena + A_WIOU + (size_t)colh * HB + quad * 8;
    const short* pO = pI + 65536;
    const short* pU = pI + 131072;

    f32x4 acc[4][3];
    #pragma unroll
    for (int rt = 0; rt < 4; ++rt)
      #pragma unroll
      for (int g = 0; g < 3; ++g) acc[rt][g] = (f32x4){0.f,0.f,0.f,0.f};

    #pragma unroll
    for (int kk = 0; kk < 8; ++kk){
      const short8 bI = *(const short8*)(pI + kk * 32);
      const short8 bO = *(const short8*)(pO + kk * 32);
      const short8 bU = *(const short8*)(pU + kk * 32);
      #pragma unroll
      for (int rt = 0; rt < 4; ++rt){
        const int row = rh * 64 + rt * 16 + l15;
        const short8 a = *(const short8*)&At[swz(row, kk * 4 + quad)];
        acc[rt][0] = __builtin_amdgcn_mfma_f32_16x16x32_bf16(a, bI, acc[rt][0], 0, 0, 0);
        acc[rt][1] = __builtin_amdgcn_mfma_f32_16x16x32_bf16(a, bO, acc[rt][1], 0, 0, 0);
        acc[rt][2] = __builtin_amdgcn_mfma_f32_16x16x32_bf16(a, bU, acc[rt][2], 0, 0, 0);
      }
    }

    const float bi = b2f(arena[A_BIOU + colh]);
    const float bo = b2f(arena[A_BIOU + 256 + colh]);
    const float bu = b2f(arena[A_BIOU + 512 + colh]);
    #pragma unroll
    for (int rt = 0; rt < 4; ++rt){
      const f32x4 vi = acc[rt][0], vo = acc[rt][1], vu = acc[rt][2];
      #pragma unroll
      for (int r = 0; r < 4; ++r){
        const int row = rh * 64 + rt * 16 + quad * 4 + r;    // local 0..127
        const float ig = fsig(vi[r] + bi);
        const float og = fsig(vo[r] + bo);
        const float ug = ftanh(vu[r] + bu);
        const float cv = ig * ug;                       // c_in = 0
        const float hv = og * ftanh(cv);
        Oh[row * 32 + cl * 16 + l15] = f2b(hv);
        Oc[row * 32 + cl * 16 + l15] = f2b(cv);
      }
    }
    __syncthreads();
    // write-out: 4 lanes cover one row's 64B contiguously -> full-line stores
    #pragma unroll
    for (int rr = 0; rr < 4; ++rr){
      const int gi = rr * 256 + t;          // 0..1023
      const int arr = gi >> 9;              // 0: h, 1: c
      const int u = gi & 511;               // row*4 + q
      const int row = u >> 2, q = u & 3;
      const short8 v = *(const short8*)&(arr ? Oc : Oh)[row * 32 + q * 8];
      short* dst = (arr ? cout : hall + BASE8)
                 + (size_t)(rowbase + row) * HB + s * 32 + q * 8;
      *(short8*)dst = v;
    }
    __syncthreads();
  }
}

// ---------------- level 7: 128 child rows, wave = 64 rows x 16 cols x FIOU ---------------
// grid (512), block 256. R10: LDS-bounced full-line stores.
__global__ __launch_bounds__(256, 2)
void level7_kernel(const short* __restrict__ hch, const short* __restrict__ cch,
                   const short* __restrict__ arena,
                   short* __restrict__ hout, short* __restrict__ cout)
{
  __shared__ short At[32768];
  __shared__ short Oh[2048];     // 64 parent rows x 32 cols
  __shared__ short Oc[2048];
  const int t = threadIdx.x, lane = t & 63, w = t >> 6;
  const int l15 = lane & 15, quad = lane >> 4;
  const int rh = w >> 1, cl = w & 1;
  const int rowbase = 128 * blockIdx.x;                 // child rows
  const int pbase   = 64 * blockIdx.x;                  // parent rows

  #pragma unroll
  for (int i = 0; i < 16; ++i){
    const int gi = i * 256 + t;
    const int row = gi >> 5, g = gi & 31;
    *(short8*)&At[swz(row, g)] =
        *(const short8*)(hch + (size_t)(rowbase + row) * HB + g * 8);
  }
  __syncthreads();

  #pragma unroll
  for (int s = 0; s < 8; ++s){
    const int colh = s * 32 + cl * 16 + l15;
    const short* pF = arena + A_UFW  + (size_t)colh * HB + quad * 8;
    const short* pI = arena + A_UIOU + (size_t)colh * HB + quad * 8;
    const short* pO = pI + 65536;
    const short* pU = pI + 131072;

    f32x4 acc[4][4];
    #pragma unroll
    for (int rt = 0; rt < 4; ++rt)
      #pragma unroll
      for (int g = 0; g < 4; ++g) acc[rt][g] = (f32x4){0.f,0.f,0.f,0.f};

    #pragma unroll
    for (int kk = 0; kk < 8; ++kk){
      const short8 bF = *(const short8*)(pF + kk * 32);
      const short8 bI = *(const short8*)(pI + kk * 32);
      const short8 bO = *(const short8*)(pO + kk * 32);
      const short8 bU = *(const short8*)(pU + kk * 32);
      #pragma unroll
      for (int rt = 0; rt < 4; ++rt){
        const int row = rh * 64 + rt * 16 + l15;
        const short8 a = *(const short8*)&At[swz(row, kk * 4 + quad)];
        acc[rt][0] = __builtin_amdgcn_mfma_f32_16x16x32_bf16(a, bF, acc[rt][0], 0, 0, 0);
        acc[rt][1] = __builtin_amdgcn_mfma_f32_16x16x32_bf16(a, bI, acc[rt][1], 0, 0, 0);
        acc[rt][2] = __builtin_amdgcn_mfma_f32_16x16x32_bf16(a, bO, acc[rt][2], 0, 0, 0);
        acc[rt][3] = __builtin_amdgcn_mfma_f32_16x16x32_bf16(a, bU, acc[rt][3], 0, 0, 0);
      }
    }

    const float bf = b2f(arena[A_UFB + colh]);
    const float bi = b2f(arena[A_BIOU + colh]);
    const float bo = b2f(arena[A_BIOU + 256 + colh]);
    const float bu = b2f(arena[A_BIOU + 512 + colh]);
    #pragma unroll
    for (int rt = 0; rt < 4; ++rt){
      const int rloc = rh * 64 + rt * 16 + quad * 4;
      const size_t crow = (size_t)(rowbase + rloc) * HB + colh;
      const float c0 = b2f(cch[crow]);
      const float c1 = b2f(cch[crow + HB]);
      const float c2 = b2f(cch[crow + 2 * HB]);
      const float c3 = b2f(cch[crow + 3 * HB]);
      const f32x4 dF = acc[rt][0], dI = acc[rt][1], dO = acc[rt][2], dU = acc[rt][3];
      const int p0 = rloc >> 1;                         // local parent row 0..63
      {
        const float ca = fsig(dF[0] + bf) * c0 + fsig(dF[1] + bf) * c1;
        const float ig = fsig(dI[0] + dI[1] + bi);
        const float og = fsig(dO[0] + dO[1] + bo);
        const float ug = ftanh(dU[0] + dU[1] + bu);
        const float cv = ig * ug + ca;
        const float hv = og * ftanh(cv);
        Oh[p0 * 32 + cl * 16 + l15] = f2b(hv);
        Oc[p0 * 32 + cl * 16 + l15] = f2b(cv);
      }
      {
        const float ca = fsig(dF[2] + bf) * c2 + fsig(dF[3] + bf) * c3;
        const float ig = fsig(dI[2] + dI[3] + bi);
        const float og = fsig(dO[2] + dO[3] + bo);
        const float ug = ftanh(dU[2] + dU[3] + bu);
        const float cv = ig * ug + ca;
        const float hv = og * ftanh(cv);
        Oh[(p0 + 1) * 32 + cl * 16 + l15] = f2b(hv);
        Oc[(p0 + 1) * 32 + cl * 16 + l15] = f2b(cv);
      }
    }
    __syncthreads();
    #pragma unroll
    for (int rr = 0; rr < 2; ++rr){
      const int gi = rr * 256 + t;          // 0..511
      const int arr = gi >> 8;              // 0: h, 1: c
      const int u = gi & 255;               // row*4 + q
      const int row = u >> 2, q = u & 3;
      const short8 v = *(const short8*)&(arr ? Oc : Oh)[row * 32 + q * 8];
      short* dst = (arr ? cout : hout)
                 + (size_t)(pbase + row) * HB + s * 32 + q * 8;
      *(short8*)dst = v;
    }
    __syncthreads();
  }
}

// ---------------- fused tail: levels d=6..0 + reduction + head MLP, 1 block/batch --------
// 1024 threads (16 waves, 1 block/CU by LDS). Weights read in-loop from arena
// (L2-resident, shared by all blocks) — NO register hoist (R9 spilled).
// LDS (157,056 B): HA 128x264, HBf 64x264, CBf 64x264, CAf 32x264 (bf16),
// scol[256], lastr[256], sx[544], sy1[128], sy2[64] (f32).
__global__ __launch_bounds__(1024, 4)
void fused_kernel(const short* __restrict__ hall, const short* __restrict__ c7g,
                  const short* __restrict__ arena, const int* __restrict__ flag,
                  void* __restrict__ outv)
{
  extern __shared__ char smem[];
  short* HA   = (short*)smem;                 // 128*264*2 = 67584 B
  short* HBf  = (short*)(smem + 67584);       // 64*264*2  = 33792 B
  short* CBf  = (short*)(smem + 101376);      // 33792 B (also f32 red scratch)
  short* CAf  = (short*)(smem + 135168);      // 16896 B -> 152064
  float* scol = (float*)(smem + 152064);      // 1024 B
  float* lastr= (float*)(smem + 153088);      // 1024 B
  float* sx   = (float*)(smem + 154112);      // 2176 B
  float* sy1  = (float*)(smem + 156288);      // 512 B
  float* sy2  = (float*)(smem + 156800);      // 256 B -> 157056

  const int t = threadIdx.x, lane = t & 63, w = t >> 6;
  const int l15 = lane & 15, quad = lane >> 4;
  const int b = blockIdx.x;

  // ---- stage h7 (128 x 256) into HA (stride 264) ----
  const short* h7 = hall + BASE7 + (size_t)b * 128 * HB;
  #pragma unroll
  for (int i = 0; i < 4; ++i){
    const int gi = i * 1024 + t;
    const int row = gi >> 5, g = gi & 31;
    *(short8*)&HA[row * 264 + g * 8] = *(const short8*)(h7 + (size_t)row * HB + g * 8);
  }

  // ---- vectorized column stream-sum of h8 (global) + h7 (LDS) ----
  const short* h8 = hall + BASE8 + (size_t)b * 256 * HB;
  const int colg = t & 31, rowg = t >> 5;
  float ps[8];
  #pragma unroll
  for (int i = 0; i < 8; ++i) ps[i] = 0.f;
  #pragma unroll
  for (int jj = 0; jj < 8; ++jj){
    const int j = rowg + jj * 32;
    const short8 v = *(const short8*)(h8 + (size_t)j * HB + colg * 8);
    #pragma unroll
    for (int i = 0; i < 8; ++i) ps[i] += b2f(v[i]);
  }
  __syncthreads();                             // HA staged; now sum h7 from LDS
  #pragma unroll
  for (int jj = 0; jj < 4; ++jj){
    const int j = rowg + jj * 32;
    const short8 v = *(const short8*)&HA[j * 264 + colg * 8];
    #pragma unroll
    for (int i = 0; i < 8; ++i) ps[i] += b2f(v[i]);
  }
  {
    float* red = (float*)CBf;                  // 32 KB scratch (free until level 6)
    f32x4 lo = (f32x4){ps[0], ps[1], ps[2], ps[3]};
    f32x4 hi = (f32x4){ps[4], ps[5], ps[6], ps[7]};
    *(f32x4*)&red[rowg * 256 + colg * 8]     = lo;
    *(f32x4*)&red[rowg * 256 + colg * 8 + 4] = hi;
  }
  if (t < 256) lastr[t] = b2f(h8[(size_t)255 * HB + t]);
  __syncthreads();
  if (t < 256){
    const float* red = (const float*)CBf;
    float s = 0.f;
    #pragma unroll
    for (int g = 0; g < 32; ++g) s += red[g * 256 + t];
    scol[t] = s;
  }
  __syncthreads();                             // red (CBf) free after this

  // ---- per-wave column ownership: 16 waves x 16 cols = 256 cols, ONE pass ----
  const int colh = w * 16 + l15;
  const short* pF = arena + A_UFW  + (size_t)colh * HB + quad * 8;
  const short* pI = arena + A_UIOU + (size_t)colh * HB + quad * 8;
  const short* pO = pI + 65536;
  const short* pU = pI + 131072;
  const float bfb = b2f(arena[A_UFB + colh]);
  const float bi  = b2f(arena[A_BIOU + colh]);
  const float bo  = b2f(arena[A_BIOU + 256 + colh]);
  const float bu  = b2f(arena[A_BIOU + 512 + colh]);

  // ---- level recursion d = 6..0 ----
  for (int d = 6; d >= 0; --d){
    const int n_ch = 2 << d;
    const int n_p  = 1 << d;
    const short* hin  = (d & 1) ? HBf : HA;    // level d+1 output
    short*       hout = (d & 1) ? HA  : HBf;
    const short* cin  = (d & 1) ? CBf : CAf;
    short*       cl_  = (d & 1) ? CAf : CBf;
    const bool cglob = (d == 6);
    const int nchunk = (n_ch + 31) >> 5;

    for (int rc = 0; rc < nchunk; ++rc){
      f32x4 acc[2][4];
      #pragma unroll
      for (int rt = 0; rt < 2; ++rt)
        #pragma unroll
        for (int g = 0; g < 4; ++g) acc[rt][g] = (f32x4){0.f,0.f,0.f,0.f};

      #pragma unroll
      for (int kk = 0; kk < 8; ++kk){
        const short8 vF = *(const short8*)(pF + kk * 32);
        const short8 vI = *(const short8*)(pI + kk * 32);
        const short8 vO = *(const short8*)(pO + kk * 32);
        const short8 vU = *(const short8*)(pU + kk * 32);
        #pragma unroll
        for (int rt = 0; rt < 2; ++rt){
          const int row = rc * 32 + rt * 16 + l15;
          const short8 a = *(const short8*)&hin[row * 264 + kk * 32 + quad * 8];
          acc[rt][0] = __builtin_amdgcn_mfma_f32_16x16x32_bf16(a, vF, acc[rt][0], 0, 0, 0);
          acc[rt][1] = __builtin_amdgcn_mfma_f32_16x16x32_bf16(a, vI, acc[rt][1], 0, 0, 0);
          acc[rt][2] = __builtin_amdgcn_mfma_f32_16x16x32_bf16(a, vO, acc[rt][2], 0, 0, 0);
          acc[rt][3] = __builtin_amdgcn_mfma_f32_16x16x32_bf16(a, vU, acc[rt][3], 0, 0, 0);
        }
      }

      #pragma unroll
      for (int rt = 0; rt < 2; ++rt){
        const int rloc = rc * 32 + rt * 16 + quad * 4;   // child row, mult of 4
        if (rloc < n_ch){
          float c0, c1, c2, c3;
          if (cglob){
            const size_t crow = (size_t)(b * 128 + rloc) * HB + colh;
            c0 = b2f(c7g[crow]);           c1 = b2f(c7g[crow + HB]);
            c2 = b2f(c7g[crow + 2 * HB]);  c3 = b2f(c7g[crow + 3 * HB]);
          } else {
            c0 = b2f(cin[(rloc    ) * 264 + colh]);
            c1 = b2f(cin[(rloc + 1) * 264 + colh]);
            c2 = b2f(cin[(rloc + 2) * 264 + colh]);
            c3 = b2f(cin[(rloc + 3) * 264 + colh]);
          }
          const f32x4 dF = acc[rt][0], dI = acc[rt][1], dO = acc[rt][2], dU = acc[rt][3];
          const int p0 = rloc >> 1;
          {
            const float ca = fsig(dF[0] + bfb) * c0 + fsig(dF[1] + bfb) * c1;
            const float ig = fsig(dI[0] + dI[1] + bi);
            const float og = fsig(dO[0] + dO[1] + bo);
            const float ug = ftanh(dU[0] + dU[1] + bu);
            const float cv = ig * ug + ca;
            const float hv = og * ftanh(cv);
            hout[p0 * 264 + colh] = f2b(hv);
            cl_[p0 * 264 + colh]  = f2b(cv);
          }
          if (rloc + 2 < n_ch){
            const float ca = fsig(dF[2] + bfb) * c2 + fsig(dF[3] + bfb) * c3;
            const float ig = fsig(dI[2] + dI[3] + bi);
            const float og = fsig(dO[2] + dO[3] + bo);
            const float ug = ftanh(dU[2] + dU[3] + bu);
            const float cv = ig * ug + ca;
            const float hv = og * ftanh(cv);
            hout[(p0 + 1) * 264 + colh] = f2b(hv);
            cl_[(p0 + 1) * 264 + colh]  = f2b(cv);
          }
        }
      }
    }
    __syncthreads();
    // accumulate this level's h into scol (thread t owns col t)
    if (t < 256){
      float s2 = 0.f;
      for (int r = 0; r < n_p; ++r) s2 += b2f(hout[r * 264 + t]);
      scol[t] += s2;
    }
    __syncthreads();
  }

  // ---- assemble x2 = [head | inner | emo] ----
  if (t < 256){
    const float head = b2f(HBf[t]);            // h0 -> B region, row 0
    sx[t]       = head;
    sx[256 + t] = (scol[t] - head - lastr[t]) * (1.f / 509.f);
  }
  if (t < 32) sx[512 + t] = b2f(arena[A_EMO + b * 32 + t]);
  __syncthreads();

  // ---- head MLP 544 -> 128 -> 64 -> 4, K split across lanes + shfl reduce ----
  {
    // y1: 128 outputs x 8 lanes; each lane covers 68 k via 17 short4 loads
    const int o = t >> 3, p = t & 7;
    const short* wr = arena + A_WIN + (size_t)o * 544 + p * 68;
    const float* xk = sx + p * 68;
    float a = 0.f;
    #pragma unroll
    for (int i = 0; i < 17; ++i){
      const short4 wv = *(const short4*)(wr + i * 4);
      a += xk[i*4    ] * b2f(wv.x);
      a += xk[i*4 + 1] * b2f(wv.y);
      a += xk[i*4 + 2] * b2f(wv.z);
      a += xk[i*4 + 3] * b2f(wv.w);
    }
    a += __shfl_xor(a, 1); a += __shfl_xor(a, 2); a += __shfl_xor(a, 4);
    if (p == 0) sy1[o] = fmaxf(a + b2f(arena[A_BIN + o]), 0.f);
  }
  __syncthreads();
  {
    // y2: 64 outputs x 16 lanes; each lane covers 8 k via one short8 load
    const int o = t >> 4, p = t & 15;
    const short8 wv = *(const short8*)(arena + A_WMID + (size_t)o * 128 + p * 8);
    float a = 0.f;
    #pragma unroll
    for (int i = 0; i < 8; ++i) a += sy1[p * 8 + i] * b2f(wv[i]);
    a += __shfl_xor(a, 1); a += __shfl_xor(a, 2);
    a += __shfl_xor(a, 4); a += __shfl_xor(a, 8);
    if (p == 0) sy2[o] = fmaxf(a + b2f(arena[A_BMID + o]), 0.f);
  }
  __syncthreads();
  if (t < 64){
    // out: 4 outputs x 16 lanes; each lane covers 4 k via one short4 load
    const int o = t >> 4, p = t & 15;
    const short4 wv = *(const short4*)(arena + A_WOUT + o * 64 + p * 4);
    float a = sy2[p*4    ] * b2f(wv.x) + sy2[p*4 + 1] * b2f(wv.y)
            + sy2[p*4 + 2] * b2f(wv.z) + sy2[p*4 + 3] * b2f(wv.w);
    a += __shfl_xor(a, 1); a += __shfl_xor(a, 2);
    a += __shfl_xor(a, 4); a += __shfl_xor(a, 8);
    if (p == 0){
      const float sg = fsig(a + b2f(arena[A_BOUT + o]));
      if (*flag) ((float*)outv)[(size_t)b * 4 + o] = sg;
      else       ((short*)outv)[(size_t)b * 4 + o] = f2b(sg);
    }
  }
}

extern "C" void kernel_launch(void* const* d_in, const int* in_sizes, int n_in,
                              void* d_out, int out_size, void* d_ws, size_t ws_size,
                              hipStream_t stream)
{
  (void)in_sizes; (void)n_in; (void)out_size; (void)ws_size;
  const void* X    = d_in[0];
  const void* emo  = d_in[3];
  const void* Wiou = d_in[4];
  const void* Uiou = d_in[5];
  const void* biou = d_in[6];
  const void* Ufw  = d_in[7];
  const void* Ufb  = d_in[8];
  const void* Win  = d_in[9];
  const void* bin  = d_in[10];
  const void* Wmid = d_in[11];
  const void* bmid = d_in[12];
  const void* Wout = d_in[13];
  const void* bout = d_in[14];

  char* ws = (char*)d_ws;
  short* h_all = (short*)ws;
  short* cbufA = (short*)(ws + 66977792);
  short* cbufB = (short*)(ws + 100532224);
  short* arena = (short*)(ws + 117309440);
  int*   flag  = (int*)  (ws + 118401928);

  const int FUSED_LDS = 157056;
  hipFuncSetAttribute((const void*)fused_kernel,
                      hipFuncAttributeMaxDynamicSharedMemorySize, FUSED_LDS);

  dim3 blk(256);

  probe_kernel<<<dim3(1), blk, 0, stream>>>(X, flag);
  conv_kernel<<<dim3((A_TOT + 255) / 256), blk, 0, stream>>>(
      Wiou, Uiou, biou, Ufw, Ufb, Win, bin, Wmid, bmid, Wout, bout, emo, arena, flag);

  leaf_kernel<<<dim3(512), blk, 0, stream>>>(X, arena, flag, h_all, cbufA);

  // level 7: children = level 8 (65536 rows), c8 in cbufA -> h7, c7 (cbufB)
  level7_kernel<<<dim3(512), blk, 0, stream>>>(h_all + BASE8, cbufA, arena,
                                               h_all + BASE7, cbufB);

  // levels 6..0 + reduction + head, one block per batch element, 16 waves
  fused_kernel<<<dim3(256), dim3(1024), FUSED_LDS, stream>>>(h_all, cbufB, arena, flag, d_out);
}

// Round 4
// 643.406 us; speedup vs baseline: 1.5082x; 1.5082x over previous
//
#include <hip/hip_runtime.h>

// DeepTreeLSTM on MI355X (gfx950). Inputs fp32 (verified R3); dtype probe kept.
// Tree: 511 nodes, level d has 2^d nodes. h level-major: base_d = 256*(2^d-1)*256.
//
// R11: fused spilled ~1GB scratch (R10 counters: FETCH 564MB, WRITE 494MB, VGPR=64).
// Root cause: arena is const __restrict__ -> compiler PROVES weight loads invariant
// across the whole d-loop, hoists 128 VGPRs of weights, spills at the 1024-thread
// 128-VGPR cap. Fix: (a) launder weight pointers through empty asm per chunk so
// invariance is unprovable; (b) per-gate sub-loops so max live weight regs = 32.
//
// Workspace:
//   h_all  bf16 [0,           66,977,792)    (only levels 7,8 written now)
//   cbufA  bf16 [66,977,792, 100,532,224)   c8 (leaf out)
//   cbufB  bf16 [100,532,224,117,309,440)   c7 (level7 out)
//   arena  bf16 [117,309,440,118,401,928)   converted weights/biases/emo
//   flag   int  [118,401,928,118,401,932)

typedef __attribute__((ext_vector_type(8))) short short8;
typedef __attribute__((ext_vector_type(4))) float f32x4;

#define HB 256
#define BASE8 16711680   // 256*255*256
#define BASE7 8323072    // 256*127*256

#define A_WIOU 0
#define A_UIOU 196608
#define A_BIOU 393216
#define A_UFW  393984
#define A_UFB  459520
#define A_WIN  459776
#define A_BIN  529408
#define A_WMID 529536
#define A_BMID 537728
#define A_WOUT 537792
#define A_BOUT 538048
#define A_EMO  538052
#define A_TOT  546244

__device__ __forceinline__ float b2f(short s){
  union { unsigned u; float f; } v; v.u = ((unsigned)(unsigned short)s) << 16; return v.f;
}
__device__ __forceinline__ short f2b(float f){
  union { float f; unsigned u; } v; v.f = f;
  unsigned r = v.u + 0x7fffu + ((v.u >> 16) & 1u);   // RNE
  return (short)(unsigned short)(r >> 16);
}
__device__ __forceinline__ float fsig(float x){ return 1.f / (1.f + __expf(-x)); }
__device__ __forceinline__ float ftanh(float x){
  x = fminf(fmaxf(x, -10.f), 10.f);
  float e = __expf(2.f * x);
  return (e - 1.f) / (e + 1.f);
}

// LDS A-tile (leaf/level7): 128 rows x 256 k, XOR-swizzled 8-short groups (64 KB).
__device__ __forceinline__ int swz(int row, int g){   // g = k>>3
  return row * 256 + (((g ^ (row & 31)) & 31) << 3);
}

// ---------------- dtype probe ------------------------------------------------------------
__global__ __launch_bounds__(256)
void probe_kernel(const void* __restrict__ X, int* __restrict__ flag)
{
  __shared__ int sh[256];
  const int t = threadIdx.x;
  const unsigned short* p = (const unsigned short*)X;
  int cnt = 0;
  #pragma unroll
  for (int k = 0; k < 16; ++k){
    unsigned e = (p[t * 16 + k] >> 7) & 0xFFu;
    cnt += (e >= 0xC0u);
  }
  sh[t] = cnt; __syncthreads();
  for (int s = 128; s > 0; s >>= 1){ if (t < s) sh[t] += sh[t + s]; __syncthreads(); }
  if (t == 0) *flag = (sh[0] >= 16) ? 1 : 0;
}

// ---------------- convert params into bf16 arena -----------------------------------------
__global__ __launch_bounds__(256)
void conv_kernel(const void* s0, const void* s1, const void* s2, const void* s3,
                 const void* s4, const void* s5, const void* s6, const void* s7,
                 const void* s8, const void* s9, const void* s10, const void* s11,
                 short* __restrict__ arena, const int* __restrict__ flag)
{
  const int i = blockIdx.x * 256 + threadIdx.x;
  if (i >= A_TOT) return;
  const int bounds[13] = {A_WIOU, A_UIOU, A_BIOU, A_UFW, A_UFB, A_WIN, A_BIN,
                          A_WMID, A_BMID, A_WOUT, A_BOUT, A_EMO, A_TOT};
  const void* sp[12] = {s0,s1,s2,s3,s4,s5,s6,s7,s8,s9,s10,s11};
  int seg = 0;
  #pragma unroll
  for (int k = 1; k < 12; ++k) if (i >= bounds[k]) seg = k;
  const int j = i - bounds[seg];
  const float v = (*flag) ? ((const float*)sp[seg])[j] : b2f(((const short*)sp[seg])[j]);
  arena[i] = f2b(v);
}

// ---------------- leaf: 128-row tile, wave = 64 rows x 16 cols x 3 gates -----------------
// grid (512), block 256. Outputs bounce through LDS, stored as full 64B lines.
__global__ __launch_bounds__(256, 2)
void leaf_kernel(const void* __restrict__ X, const short* __restrict__ arena,
                 const int* __restrict__ flag,
                 short* __restrict__ hall, short* __restrict__ cout)
{
  __shared__ short At[32768];
  __shared__ short Oh[4096];     // 128 rows x 32 cols (current s-slice)
  __shared__ short Oc[4096];
  const int t = threadIdx.x, lane = t & 63, w = t >> 6;
  const int l15 = lane & 15, quad = lane >> 4;
  const int rh = w >> 1, cl = w & 1;
  const int rowbase = 128 * blockIdx.x;
  const size_t grow0 = ((size_t)(rowbase >> 8) * 511 + 255 + (rowbase & 255)) * HB;
  const bool isf = (*flag) != 0;

  #pragma unroll
  for (int i = 0; i < 16; ++i){
    const int gi = i * 256 + t;
    const int row = gi >> 5, g = gi & 31;
    short8 v;
    if (isf){
      const float* p = (const float*)X + grow0 + (size_t)row * HB + g * 8;
      const float4 u = *(const float4*)p;
      const float4 q = *(const float4*)(p + 4);
      v[0]=f2b(u.x); v[1]=f2b(u.y); v[2]=f2b(u.z); v[3]=f2b(u.w);
      v[4]=f2b(q.x); v[5]=f2b(q.y); v[6]=f2b(q.z); v[7]=f2b(q.w);
    } else {
      v = *(const short8*)((const short*)X + grow0 + (size_t)row * HB + g * 8);
    }
    *(short8*)&At[swz(row, g)] = v;
  }
  __syncthreads();

  #pragma unroll
  for (int s = 0; s < 8; ++s){
    const int colh = s * 32 + cl * 16 + l15;
    const short* pI = arena + A_WIOU + (size_t)colh * HB + quad * 8;
    const short* pO = pI + 65536;
    const short* pU = pI + 131072;

    f32x4 acc[4][3];
    #pragma unroll
    for (int rt = 0; rt < 4; ++rt)
      #pragma unroll
      for (int g = 0; g < 3; ++g) acc[rt][g] = (f32x4){0.f,0.f,0.f,0.f};

    #pragma unroll
    for (int kk = 0; kk < 8; ++kk){
      const short8 bI = *(const short8*)(pI + kk * 32);
      const short8 bO = *(const short8*)(pO + kk * 32);
      const short8 bU = *(const short8*)(pU + kk * 32);
      #pragma unroll
      for (int rt = 0; rt < 4; ++rt){
        const int row = rh * 64 + rt * 16 + l15;
        const short8 a = *(const short8*)&At[swz(row, kk * 4 + quad)];
        acc[rt][0] = __builtin_amdgcn_mfma_f32_16x16x32_bf16(a, bI, acc[rt][0], 0, 0, 0);
        acc[rt][1] = __builtin_amdgcn_mfma_f32_16x16x32_bf16(a, bO, acc[rt][1], 0, 0, 0);
        acc[rt][2] = __builtin_amdgcn_mfma_f32_16x16x32_bf16(a, bU, acc[rt][2], 0, 0, 0);
      }
    }

    const float bi = b2f(arena[A_BIOU + colh]);
    const float bo = b2f(arena[A_BIOU + 256 + colh]);
    const float bu = b2f(arena[A_BIOU + 512 + colh]);
    #pragma unroll
    for (int rt = 0; rt < 4; ++rt){
      const f32x4 vi = acc[rt][0], vo = acc[rt][1], vu = acc[rt][2];
      #pragma unroll
      for (int r = 0; r < 4; ++r){
        const int row = rh * 64 + rt * 16 + quad * 4 + r;    // local 0..127
        const float ig = fsig(vi[r] + bi);
        const float og = fsig(vo[r] + bo);
        const float ug = ftanh(vu[r] + bu);
        const float cv = ig * ug;                       // c_in = 0
        const float hv = og * ftanh(cv);
        Oh[row * 32 + cl * 16 + l15] = f2b(hv);
        Oc[row * 32 + cl * 16 + l15] = f2b(cv);
      }
    }
    __syncthreads();
    // write-out: 4 lanes cover one row's 64B contiguously -> full-line stores
    #pragma unroll
    for (int rr = 0; rr < 4; ++rr){
      const int gi = rr * 256 + t;          // 0..1023
      const int arr = gi >> 9;              // 0: h, 1: c
      const int u = gi & 511;               // row*4 + q
      const int row = u >> 2, q = u & 3;
      const short8 v = *(const short8*)&(arr ? Oc : Oh)[row * 32 + q * 8];
      short* dst = (arr ? cout : hall + BASE8)
                 + (size_t)(rowbase + row) * HB + s * 32 + q * 8;
      *(short8*)dst = v;
    }
    __syncthreads();
  }
}

// ---------------- level 7: 128 child rows, wave = 64 rows x 16 cols x FIOU ---------------
// grid (512), block 256. LDS-bounced full-line stores.
__global__ __launch_bounds__(256, 2)
void level7_kernel(const short* __restrict__ hch, const short* __restrict__ cch,
                   const short* __restrict__ arena,
                   short* __restrict__ hout, short* __restrict__ cout)
{
  __shared__ short At[32768];
  __shared__ short Oh[2048];     // 64 parent rows x 32 cols
  __shared__ short Oc[2048];
  const int t = threadIdx.x, lane = t & 63, w = t >> 6;
  const int l15 = lane & 15, quad = lane >> 4;
  const int rh = w >> 1, cl = w & 1;
  const int rowbase = 128 * blockIdx.x;                 // child rows
  const int pbase   = 64 * blockIdx.x;                  // parent rows

  #pragma unroll
  for (int i = 0; i < 16; ++i){
    const int gi = i * 256 + t;
    const int row = gi >> 5, g = gi & 31;
    *(short8*)&At[swz(row, g)] =
        *(const short8*)(hch + (size_t)(rowbase + row) * HB + g * 8);
  }
  __syncthreads();

  #pragma unroll
  for (int s = 0; s < 8; ++s){
    const int colh = s * 32 + cl * 16 + l15;
    const short* pF = arena + A_UFW  + (size_t)colh * HB + quad * 8;
    const short* pI = arena + A_UIOU + (size_t)colh * HB + quad * 8;
    const short* pO = pI + 65536;
    const short* pU = pI + 131072;

    f32x4 acc[4][4];
    #pragma unroll
    for (int rt = 0; rt < 4; ++rt)
      #pragma unroll
      for (int g = 0; g < 4; ++g) acc[rt][g] = (f32x4){0.f,0.f,0.f,0.f};

    #pragma unroll
    for (int kk = 0; kk < 8; ++kk){
      const short8 bF = *(const short8*)(pF + kk * 32);
      const short8 bI = *(const short8*)(pI + kk * 32);
      const short8 bO = *(const short8*)(pO + kk * 32);
      const short8 bU = *(const short8*)(pU + kk * 32);
      #pragma unroll
      for (int rt = 0; rt < 4; ++rt){
        const int row = rh * 64 + rt * 16 + l15;
        const short8 a = *(const short8*)&At[swz(row, kk * 4 + quad)];
        acc[rt][0] = __builtin_amdgcn_mfma_f32_16x16x32_bf16(a, bF, acc[rt][0], 0, 0, 0);
        acc[rt][1] = __builtin_amdgcn_mfma_f32_16x16x32_bf16(a, bI, acc[rt][1], 0, 0, 0);
        acc[rt][2] = __builtin_amdgcn_mfma_f32_16x16x32_bf16(a, bO, acc[rt][2], 0, 0, 0);
        acc[rt][3] = __builtin_amdgcn_mfma_f32_16x16x32_bf16(a, bU, acc[rt][3], 0, 0, 0);
      }
    }

    const float bf = b2f(arena[A_UFB + colh]);
    const float bi = b2f(arena[A_BIOU + colh]);
    const float bo = b2f(arena[A_BIOU + 256 + colh]);
    const float bu = b2f(arena[A_BIOU + 512 + colh]);
    #pragma unroll
    for (int rt = 0; rt < 4; ++rt){
      const int rloc = rh * 64 + rt * 16 + quad * 4;
      const size_t crow = (size_t)(rowbase + rloc) * HB + colh;
      const float c0 = b2f(cch[crow]);
      const float c1 = b2f(cch[crow + HB]);
      const float c2 = b2f(cch[crow + 2 * HB]);
      const float c3 = b2f(cch[crow + 3 * HB]);
      const f32x4 dF = acc[rt][0], dI = acc[rt][1], dO = acc[rt][2], dU = acc[rt][3];
      const int p0 = rloc >> 1;                         // local parent row 0..63
      {
        const float ca = fsig(dF[0] + bf) * c0 + fsig(dF[1] + bf) * c1;
        const float ig = fsig(dI[0] + dI[1] + bi);
        const float og = fsig(dO[0] + dO[1] + bo);
        const float ug = ftanh(dU[0] + dU[1] + bu);
        const float cv = ig * ug + ca;
        const float hv = og * ftanh(cv);
        Oh[p0 * 32 + cl * 16 + l15] = f2b(hv);
        Oc[p0 * 32 + cl * 16 + l15] = f2b(cv);
      }
      {
        const float ca = fsig(dF[2] + bf) * c2 + fsig(dF[3] + bf) * c3;
        const float ig = fsig(dI[2] + dI[3] + bi);
        const float og = fsig(dO[2] + dO[3] + bo);
        const float ug = ftanh(dU[2] + dU[3] + bu);
        const float cv = ig * ug + ca;
        const float hv = og * ftanh(cv);
        Oh[(p0 + 1) * 32 + cl * 16 + l15] = f2b(hv);
        Oc[(p0 + 1) * 32 + cl * 16 + l15] = f2b(cv);
      }
    }
    __syncthreads();
    #pragma unroll
    for (int rr = 0; rr < 2; ++rr){
      const int gi = rr * 256 + t;          // 0..511
      const int arr = gi >> 8;              // 0: h, 1: c
      const int u = gi & 255;               // row*4 + q
      const int row = u >> 2, q = u & 3;
      const short8 v = *(const short8*)&(arr ? Oc : Oh)[row * 32 + q * 8];
      short* dst = (arr ? cout : hout)
                 + (size_t)(pbase + row) * HB + s * 32 + q * 8;
      *(short8*)dst = v;
    }
    __syncthreads();
  }
}

// ---------------- fused tail: levels d=6..0 + reduction + head MLP, 1 block/batch --------
// 1024 threads (16 waves, 1 block/CU by LDS). R11: weight loads kept IN-LOOP via
// pointer laundering (empty asm, breaks provable invariance of const-restrict arena)
// + per-gate sub-loops (max live weight regs 32, under the 128-VGPR cap).
// LDS (157,056 B): HA 128x264, HBf 64x264, CBf 64x264, CAf 32x264 (bf16),
// scol[256], lastr[256], sx[544], sy1[128], sy2[64] (f32).
__global__ __launch_bounds__(1024, 4)
void fused_kernel(const short* __restrict__ hall, const short* __restrict__ c7g,
                  const short* __restrict__ arena, const int* __restrict__ flag,
                  void* __restrict__ outv)
{
  extern __shared__ char smem[];
  short* HA   = (short*)smem;                 // 128*264*2 = 67584 B
  short* HBf  = (short*)(smem + 67584);       // 64*264*2  = 33792 B
  short* CBf  = (short*)(smem + 101376);      // 33792 B (also f32 red scratch)
  short* CAf  = (short*)(smem + 135168);      // 16896 B -> 152064
  float* scol = (float*)(smem + 152064);      // 1024 B
  float* lastr= (float*)(smem + 153088);      // 1024 B
  float* sx   = (float*)(smem + 154112);      // 2176 B
  float* sy1  = (float*)(smem + 156288);      // 512 B
  float* sy2  = (float*)(smem + 156800);      // 256 B -> 157056

  const int t = threadIdx.x, lane = t & 63, w = t >> 6;
  const int l15 = lane & 15, quad = lane >> 4;
  const int b = blockIdx.x;

  // ---- stage h7 (128 x 256) into HA (stride 264) ----
  const short* h7 = hall + BASE7 + (size_t)b * 128 * HB;
  #pragma unroll
  for (int i = 0; i < 4; ++i){
    const int gi = i * 1024 + t;
    const int row = gi >> 5, g = gi & 31;
    *(short8*)&HA[row * 264 + g * 8] = *(const short8*)(h7 + (size_t)row * HB + g * 8);
  }

  // ---- vectorized column stream-sum of h8 (global) + h7 (LDS) ----
  const short* h8 = hall + BASE8 + (size_t)b * 256 * HB;
  const int colg = t & 31, rowg = t >> 5;
  float ps[8];
  #pragma unroll
  for (int i = 0; i < 8; ++i) ps[i] = 0.f;
  #pragma unroll
  for (int jj = 0; jj < 8; ++jj){
    const int j = rowg + jj * 32;
    const short8 v = *(const short8*)(h8 + (size_t)j * HB + colg * 8);
    #pragma unroll
    for (int i = 0; i < 8; ++i) ps[i] += b2f(v[i]);
  }
  __syncthreads();                             // HA staged; now sum h7 from LDS
  #pragma unroll
  for (int jj = 0; jj < 4; ++jj){
    const int j = rowg + jj * 32;
    const short8 v = *(const short8*)&HA[j * 264 + colg * 8];
    #pragma unroll
    for (int i = 0; i < 8; ++i) ps[i] += b2f(v[i]);
  }
  {
    float* red = (float*)CBf;                  // 32 KB scratch (free until level 6)
    f32x4 lo = (f32x4){ps[0], ps[1], ps[2], ps[3]};
    f32x4 hi = (f32x4){ps[4], ps[5], ps[6], ps[7]};
    *(f32x4*)&red[rowg * 256 + colg * 8]     = lo;
    *(f32x4*)&red[rowg * 256 + colg * 8 + 4] = hi;
  }
  if (t < 256) lastr[t] = b2f(h8[(size_t)255 * HB + t]);
  __syncthreads();
  if (t < 256){
    const float* red = (const float*)CBf;
    float s = 0.f;
    #pragma unroll
    for (int g = 0; g < 32; ++g) s += red[g * 256 + t];
    scol[t] = s;
  }
  __syncthreads();                             // red (CBf) free after this

  // ---- per-wave column ownership: 16 waves x 16 cols = 256 cols, ONE pass ----
  const int colh = w * 16 + l15;
  const short* pW[4];
  pW[0] = arena + A_UFW  + (size_t)colh * HB + quad * 8;   // F
  pW[1] = arena + A_UIOU + (size_t)colh * HB + quad * 8;   // I
  pW[2] = pW[1] + 65536;                                   // O
  pW[3] = pW[1] + 131072;                                  // U
  const float bfb = b2f(arena[A_UFB + colh]);
  const float bi  = b2f(arena[A_BIOU + colh]);
  const float bo  = b2f(arena[A_BIOU + 256 + colh]);
  const float bu  = b2f(arena[A_BIOU + 512 + colh]);

  // ---- level recursion d = 6..0 ----
  for (int d = 6; d >= 0; --d){
    const int n_ch = 2 << d;
    const int n_p  = 1 << d;
    const short* hin  = (d & 1) ? HBf : HA;    // level d+1 output
    short*       hout = (d & 1) ? HA  : HBf;
    const short* cin  = (d & 1) ? CBf : CAf;
    short*       cl_  = (d & 1) ? CAf : CBf;
    const bool cglob = (d == 6);
    const int nchunk = (n_ch + 31) >> 5;

    for (int rc = 0; rc < nchunk; ++rc){
      f32x4 acc[2][4];
      #pragma unroll
      for (int rt = 0; rt < 2; ++rt)
        #pragma unroll
        for (int g = 0; g < 4; ++g) acc[rt][g] = (f32x4){0.f,0.f,0.f,0.f};

      // per-gate sub-loops: only 8 short8 (32 VGPRs) of weights live at once.
      #pragma unroll
      for (int g = 0; g < 4; ++g){
        const short* q = pW[g];
        // launder: compiler must assume q changed -> loads can't be hoisted
        // out of the rc/d loops (arena is const-restrict, otherwise provably
        // invariant -> R10's 1GB scratch spill).
        asm volatile("" : "+v"(q));
        #pragma unroll
        for (int kk = 0; kk < 8; ++kk){
          const short8 wv = *(const short8*)(q + kk * 32);
          #pragma unroll
          for (int rt = 0; rt < 2; ++rt){
            const int row = rc * 32 + rt * 16 + l15;
            const short8 a = *(const short8*)&hin[row * 264 + kk * 32 + quad * 8];
            acc[rt][g] = __builtin_amdgcn_mfma_f32_16x16x32_bf16(a, wv, acc[rt][g], 0, 0, 0);
          }
        }
      }

      #pragma unroll
      for (int rt = 0; rt < 2; ++rt){
        const int rloc = rc * 32 + rt * 16 + quad * 4;   // child row, mult of 4
        if (rloc < n_ch){
          float c0, c1, c2, c3;
          if (cglob){
            const size_t crow = (size_t)(b * 128 + rloc) * HB + colh;
            c0 = b2f(c7g[crow]);           c1 = b2f(c7g[crow + HB]);
            c2 = b2f(c7g[crow + 2 * HB]);  c3 = b2f(c7g[crow + 3 * HB]);
          } else {
            c0 = b2f(cin[(rloc    ) * 264 + colh]);
            c1 = b2f(cin[(rloc + 1) * 264 + colh]);
            c2 = b2f(cin[(rloc + 2) * 264 + colh]);
            c3 = b2f(cin[(rloc + 3) * 264 + colh]);
          }
          const f32x4 dF = acc[rt][0], dI = acc[rt][1], dO = acc[rt][2], dU = acc[rt][3];
          const int p0 = rloc >> 1;
          {
            const float ca = fsig(dF[0] + bfb) * c0 + fsig(dF[1] + bfb) * c1;
            const float ig = fsig(dI[0] + dI[1] + bi);
            const float og = fsig(dO[0] + dO[1] + bo);
            const float ug = ftanh(dU[0] + dU[1] + bu);
            const float cv = ig * ug + ca;
            const float hv = og * ftanh(cv);
            hout[p0 * 264 + colh] = f2b(hv);
            cl_[p0 * 264 + colh]  = f2b(cv);
          }
          if (rloc + 2 < n_ch){
            const float ca = fsig(dF[2] + bfb) * c2 + fsig(dF[3] + bfb) * c3;
            const float ig = fsig(dI[2] + dI[3] + bi);
            const float og = fsig(dO[2] + dO[3] + bo);
            const float ug = ftanh(dU[2] + dU[3] + bu);
            const float cv = ig * ug + ca;
            const float hv = og * ftanh(cv);
            hout[(p0 + 1) * 264 + colh] = f2b(hv);
            cl_[(p0 + 1) * 264 + colh]  = f2b(cv);
          }
        }
      }
    }
    __syncthreads();
    // accumulate this level's h into scol (thread t owns col t)
    if (t < 256){
      float s2 = 0.f;
      for (int r = 0; r < n_p; ++r) s2 += b2f(hout[r * 264 + t]);
      scol[t] += s2;
    }
    __syncthreads();
  }

  // ---- assemble x2 = [head | inner | emo] ----
  if (t < 256){
    const float head = b2f(HBf[t]);            // h0 -> B region, row 0
    sx[t]       = head;
    sx[256 + t] = (scol[t] - head - lastr[t]) * (1.f / 509.f);
  }
  if (t < 32) sx[512 + t] = b2f(arena[A_EMO + b * 32 + t]);
  __syncthreads();

  // ---- head MLP 544 -> 128 -> 64 -> 4, K split across lanes + shfl reduce ----
  {
    // y1: 128 outputs x 8 lanes; each lane covers 68 k via 17 short4 loads
    const int o = t >> 3, p = t & 7;
    const short* wr = arena + A_WIN + (size_t)o * 544 + p * 68;
    const float* xk = sx + p * 68;
    float a = 0.f;
    #pragma unroll
    for (int i = 0; i < 17; ++i){
      const short4 wv = *(const short4*)(wr + i * 4);
      a += xk[i*4    ] * b2f(wv.x);
      a += xk[i*4 + 1] * b2f(wv.y);
      a += xk[i*4 + 2] * b2f(wv.z);
      a += xk[i*4 + 3] * b2f(wv.w);
    }
    a += __shfl_xor(a, 1); a += __shfl_xor(a, 2); a += __shfl_xor(a, 4);
    if (p == 0) sy1[o] = fmaxf(a + b2f(arena[A_BIN + o]), 0.f);
  }
  __syncthreads();
  {
    // y2: 64 outputs x 16 lanes; each lane covers 8 k via one short8 load
    const int o = t >> 4, p = t & 15;
    const short8 wv = *(const short8*)(arena + A_WMID + (size_t)o * 128 + p * 8);
    float a = 0.f;
    #pragma unroll
    for (int i = 0; i < 8; ++i) a += sy1[p * 8 + i] * b2f(wv[i]);
    a += __shfl_xor(a, 1); a += __shfl_xor(a, 2);
    a += __shfl_xor(a, 4); a += __shfl_xor(a, 8);
    if (p == 0) sy2[o] = fmaxf(a + b2f(arena[A_BMID + o]), 0.f);
  }
  __syncthreads();
  if (t < 64){
    // out: 4 outputs x 16 lanes; each lane covers 4 k via one short4 load
    const int o = t >> 4, p = t & 15;
    const short4 wv = *(const short4*)(arena + A_WOUT + o * 64 + p * 4);
    float a = sy2[p*4    ] * b2f(wv.x) + sy2[p*4 + 1] * b2f(wv.y)
            + sy2[p*4 + 2] * b2f(wv.z) + sy2[p*4 + 3] * b2f(wv.w);
    a += __shfl_xor(a, 1); a += __shfl_xor(a, 2);
    a += __shfl_xor(a, 4); a += __shfl_xor(a, 8);
    if (p == 0){
      const float sg = fsig(a + b2f(arena[A_BOUT + o]));
      if (*flag) ((float*)outv)[(size_t)b * 4 + o] = sg;
      else       ((short*)outv)[(size_t)b * 4 + o] = f2b(sg);
    }
  }
}

extern "C" void kernel_launch(void* const* d_in, const int* in_sizes, int n_in,
                              void* d_out, int out_size, void* d_ws, size_t ws_size,
                              hipStream_t stream)
{
  (void)in_sizes; (void)n_in; (void)out_size; (void)ws_size;
  const void* X    = d_in[0];
  const void* emo  = d_in[3];
  const void* Wiou = d_in[4];
  const void* Uiou = d_in[5];
  const void* biou = d_in[6];
  const void* Ufw  = d_in[7];
  const void* Ufb  = d_in[8];
  const void* Win  = d_in[9];
  const void* bin  = d_in[10];
  const void* Wmid = d_in[11];
  const void* bmid = d_in[12];
  const void* Wout = d_in[13];
  const void* bout = d_in[14];

  char* ws = (char*)d_ws;
  short* h_all = (short*)ws;
  short* cbufA = (short*)(ws + 66977792);
  short* cbufB = (short*)(ws + 100532224);
  short* arena = (short*)(ws + 117309440);
  int*   flag  = (int*)  (ws + 118401928);

  const int FUSED_LDS = 157056;
  hipFuncSetAttribute((const void*)fused_kernel,
                      hipFuncAttributeMaxDynamicSharedMemorySize, FUSED_LDS);

  dim3 blk(256);

  probe_kernel<<<dim3(1), blk, 0, stream>>>(X, flag);
  conv_kernel<<<dim3((A_TOT + 255) / 256), blk, 0, stream>>>(
      Wiou, Uiou, biou, Ufw, Ufb, Win, bin, Wmid, bmid, Wout, bout, emo, arena, flag);

  leaf_kernel<<<dim3(512), blk, 0, stream>>>(X, arena, flag, h_all, cbufA);

  // level 7: children = level 8 (65536 rows), c8 in cbufA -> h7, c7 (cbufB)
  level7_kernel<<<dim3(512), blk, 0, stream>>>(h_all + BASE8, cbufA, arena,
                                               h_all + BASE7, cbufB);

  // levels 6..0 + reduction + head, one block per batch element, 16 waves
  fused_kernel<<<dim3(256), dim3(1024), FUSED_LDS, stream>>>(h_all, cbufB, arena, flag, d_out);
}